// Round 4
// baseline (960.971 us; speedup 1.0000x reference)
//
#include <hip/hip_runtime.h>

#define BB 4
#define S 128
#define SS (S*S)
#define BSS (BB*SS)

__device__ __forceinline__ int off3(int b, int i, int j) { return (b * S + i) * S + j; }
__device__ __forceinline__ int off4(int b, int i, int j, int k) { return ((b * S + i) * S + j) * S + k; }

// ---------------------------------------------------------------------------
// sigmoid + LDS-tiled transpose (coalesced stores both ways).
// ws planes: qb[0], qe[1], qs[2], qbT[3], qeT[4], qsT[5], each BSS floats.
// ---------------------------------------------------------------------------
__global__ __launch_bounds__(256) void k_sigmoid(const float* __restrict__ sb,
                                                 const float* __restrict__ se,
                                                 const float* __restrict__ ss,
                                                 float* base,
                                                 float* __restrict__ ws, int init) {
    const int b = blockIdx.z, p = blockIdx.y;
    const int ti = blockIdx.x >> 2, tj = blockIdx.x & 3;
    const int col = threadIdx.x & 31, r0 = threadIdx.x >> 5;
    const float* src = (p == 0) ? sb : (p == 1) ? se : ss;

    __shared__ float tile[32][33];
#pragma unroll
    for (int rr = 0; rr < 4; ++rr) {
        const int row = r0 + 8 * rr;
        const int gi = 32 * ti + row, gj = 32 * tj + col;
        const float x = src[off3(b, gi, gj)];
        const float q = 1.0f / (1.0f + __expf(-x));
        ws[p * BSS + off3(b, gi, gj)] = q;
        if (init) base[p * BSS + off3(b, gi, gj)] = x;
        tile[row][col] = q;
    }
    __syncthreads();
#pragma unroll
    for (int rr = 0; rr < 4; ++rr) {
        const int rowo = r0 + 8 * rr;
        ws[(3 + p) * BSS + off3(b, 32 * tj + rowo, 32 * ti + col)] = tile[col][rowo];
    }
}

// ---------------------------------------------------------------------------
// 2-unit software-pipelined term kernel. grid = (2304).
// bx < 1792: units u = 2*bx+k, y=u>>9 in 0..6, b=(u>>7)&3, I=u&127 (I0,I0+1).
//   Per unit: dots(k) -> issue loads(k+1) -> reduce(k) -> atomics(k).
//   y==2/5: cf[16] (qT3 rows, b-dependent only) hoisted to block scope.
// bx >= 1792: units for gb/ge (y7/8), J = 8*(Jt0+k)+hw; ebits hoisted.
// Wave end-drain and block setup amortize over 2 units; loads of unit k+1
// stay in flight under reduce(k)'s ~600-cycle DS-pipe phase.
// ---------------------------------------------------------------------------
__global__ __launch_bounds__(256, 3) void k_terms(
    const float* __restrict__ be, const float* __restrict__ bb,
    const float* __restrict__ cb, const float* __restrict__ eb,
    const float* __restrict__ ee, const float* __restrict__ ce,
    const float* __restrict__ sp, const float* __restrict__ gb,
    const float* __restrict__ ge, const int* __restrict__ edge,
    const int* __restrict__ chart, const float* __restrict__ ws,
    float* __restrict__ base) {
    const int t = threadIdx.x, hw = t >> 5, lh = t & 31, l = t & 63;
    const int K = 4 * lh;

    const float* qb = ws;
    const float* qe = ws + BSS;
    const float* qs = ws + 2 * BSS;
    const float* qbT = ws + 3 * BSS;
    const float* qeT = ws + 4 * BSS;
    const float* qsT = ws + 5 * BSS;

    if (blockIdx.x < 1792) {
        const int u0 = 2 * blockIdx.x;
        const int y = u0 >> 9;
        const int b = (u0 >> 7) & 3;
        const int I0 = u0 & 127;
        const float* A;
        int plane;
        switch (y) {
            case 0: A = be; plane = 0; break;
            case 1: A = bb; plane = 0; break;
            case 2: A = cb; plane = 0; break;
            case 3: A = eb; plane = 1; break;
            case 4: A = ee; plane = 1; break;
            case 5: A = ce; plane = 1; break;
            default: A = sp; plane = 2; break;
        }
        const bool is25 = (y == 2 || y == 5);
        const float* qrow = (y == 0 || y == 4) ? qe : (y == 1 || y == 3) ? qb : qs;
        const float* qT3 = (y == 2) ? qbT : qeT;
        const int corrSel = (y == 1 || y == 4) ? 1 : (y == 6) ? 2 : 0;

        // ---- block constants ----
        unsigned long long C0lo = 0, C0hi = 0;
        int4 c0kv = make_int4(0, 0, 0, 0);
        if (y == 6) {
            C0lo = __ballot(chart[off3(b, 0, l)] != 0);
            C0hi = __ballot(chart[off3(b, 0, 64 + l)] != 0);
            c0kv = *(const int4*)&chart[off3(b, 0, K)];
        }
        float4 cf[16];  // y2/5 only: depends on (b, j, K) — NOT on I -> hoisted
        if (is25) {
#pragma unroll
            for (int jj = 0; jj < 16; ++jj)
                cf[jj] = *(const float4*)&qT3[off3(b, 8 * jj + hw, K)];
        }

        // ---- pipelined per-unit state ----
        float4 v[16];
        int eLoN = 0, eHiN = 0, phLoN = 0, phHiN = 0;
        float4 qvN = make_float4(0.f, 0.f, 0.f, 0.f);
        int4 ekvN = make_int4(0, 0, 0, 0);

        auto issue_unit = [&](int I) {
#pragma unroll
            for (int jj = 0; jj < 16; ++jj)
                v[jj] = *(const float4*)&A[off4(b, I, 8 * jj + hw, K)];
            ekvN = *(const int4*)&edge[off3(b, I, K)];
            if (y == 6) {
                const int Ip = (I + S - 1) & (S - 1);
                phLoN = chart[off3(b, Ip, l)];
                phHiN = chart[off3(b, Ip, 64 + l)];
            } else {
                eLoN = edge[off3(b, I, l)];
                eHiN = edge[off3(b, I, 64 + l)];
            }
            if (!is25) qvN = *(const float4*)&qrow[off3(b, I, K)];
        };

        issue_unit(I0);
#pragma unroll 1
        for (int k = 0; k < 2; ++k) {
            const int I = I0 + k;
            // consume prefetched mask state (before it is overwritten)
            unsigned long long Mlo, Mhi;
            if (y == 6) {
                Mlo = C0lo & __ballot(phLoN != 0);
                Mhi = C0hi & __ballot(phHiN != 0);
            } else {
                Mlo = __ballot(eLoN != 0);
                Mhi = __ballot(eHiN != 0);
                if (y == 3) {
                    if (I < 64) Mlo &= ~(1ull << I);
                    else Mhi &= ~(1ull << (I - 64));
                }
            }
            float pm[4];
            bool em[4];
#pragma unroll
            for (int c = 0; c < 4; ++c) {
                const bool ek = (&ekvN.x)[c] != 0;
                const bool c0k = (&c0kv.x)[c] != 0;
                const bool nI = (I != K + c);
                em[c] = ek && nI;
                if (y == 0 || y == 1 || y == 4) pm[c] = em[c] ? (&qvN.x)[c] : 0.f;
                else if (y == 3) pm[c] = ek ? (&qvN.x)[c] : 0.f;
                else if (y == 6) pm[c] = c0k ? (&qvN.x)[c] : 0.f;
                else pm[c] = 0.f;
            }

            // dots: consume v -> acc
            float acc[16];
            if (is25) {
#pragma unroll
                for (int jj = 0; jj < 16; ++jj) {
                    const int j = 8 * jj + hw;
                    float dot = 0.f;
#pragma unroll
                    for (int c = 0; c < 4; ++c) {
                        const float term = (&cf[jj].x)[c] * (&v[jj].x)[c];
                        dot += (em[c] && (K + c != j)) ? term : 0.f;
                    }
                    acc[jj] = dot;
                }
            } else {
#pragma unroll
                for (int jj = 0; jj < 16; ++jj) {
                    const int j = 8 * jj + hw;
                    float dot = pm[0] * v[jj].x + pm[1] * v[jj].y + pm[2] * v[jj].z +
                                pm[3] * v[jj].w;
                    const int ci = (corrSel == 0) ? 256 : (corrSel == 1) ? j : (I > j ? I : j);
#pragma unroll
                    for (int c = 0; c < 4; ++c)
                        dot -= (K + c == ci) ? pm[c] * (&v[jj].x)[c] : 0.f;
                    acc[jj] = dot;
                }
            }

            // prefetch next unit: loads fly under reduce + atomics below
            if (k < 1) issue_unit(I0 + 1);

#pragma unroll
            for (int jj = 0; jj < 16; ++jj) {
                const bool bit = (((jj < 8) ? Mlo : Mhi) >> (((jj & 7) << 3) + hw)) & 1;
                acc[jj] = bit ? acc[jj] : 0.f;
            }
#pragma unroll
            for (int o = 16; o > 0; o >>= 1) {
#pragma unroll
                for (int jj = 0; jj < 16; ++jj) acc[jj] += __shfl_xor(acc[jj], o);
            }
            if (lh == 0) {
#pragma unroll
                for (int jj = 0; jj < 16; ++jj)
                    atomicAdd(&base[plane * BSS + off3(b, I, 8 * jj + hw)], acc[jj]);
            }
        }
    } else {
        const int bx7 = blockIdx.x - 1792;
        const int u0 = 2 * bx7;
        const int y8 = u0 >> 9;  // 0 -> gb (y7), 1 -> ge (y8)
        const int b = (u0 >> 7) & 3;
        const int x7 = u0 & 127;
        const int Jt0 = x7 & 15;
        const int Is = x7 >> 4;
        const int I0 = 16 * Is;
        const float* A = (y8 == 0) ? gb : ge;
        const float* qT = (y8 == 0) ? qbT : qeT;
        const float* qJsrc = (y8 == 0) ? qs : qsT;
        const int hsh = l & 32;

        // ---- block constants ----
        const unsigned long long Mc0I = __ballot(chart[off3(b, 0, I0 + (l & 15))] != 0);
        const int4 c0Kv = *(const int4*)&chart[off3(b, 0, K)];
        bool c0K[4];
#pragma unroll
        for (int c = 0; c < 4; ++c) c0K[c] = (&c0Kv.x)[c] != 0;
        unsigned long long ebits = 0ull;  // edge[b, I0+s, K+c] != 0, bit 4s+c
#pragma unroll
        for (int s = 0; s < 16; ++s) {
            const int4 e4 = *(const int4*)&edge[off3(b, I0 + s, K)];
#pragma unroll
            for (int c = 0; c < 4; ++c)
                if ((&e4.x)[c] != 0) ebits |= (1ull << (4 * s + c));
        }

        // ---- pipelined per-unit state ----
        float4 v[16];
        float4 q_JN = make_float4(0.f, 0.f, 0.f, 0.f);
        float4 qtvN[4];
        int eColJN = 0;
        int4 chJKvN = make_int4(0, 0, 0, 0);
        int c0JN = 0;
        int chKJN[4] = {0, 0, 0, 0};

        auto issue_unit7 = [&](int J) {
#pragma unroll
            for (int s = 0; s < 16; ++s)
                v[s] = *(const float4*)&A[off4(b, I0 + s, J, K)];
            q_JN = *(const float4*)&qJsrc[off3(b, J, K)];
#pragma unroll
            for (int q4 = 0; q4 < 4; ++q4)
                qtvN[q4] = *(const float4*)&qT[off3(b, J, I0 + 4 * q4)];
            eColJN = edge[off3(b, I0 + (l & 15), J)];
            const int Jprev = (J + S - 1) & (S - 1);
            chJKvN = *(const int4*)&chart[off3(b, Jprev, K)];
            c0JN = chart[off3(b, 0, J)];
            if (y8 == 1) {
#pragma unroll
                for (int c = 0; c < 4; ++c)
                    chKJN[c] = chart[off3(b, (K + c + S - 1) & (S - 1), J)];
            }
        };

        issue_unit7(8 * Jt0 + hw);
#pragma unroll 1
        for (int k = 0; k < 2; ++k) {
            const int J = 8 * (Jt0 + k) + hw;
            const unsigned long long MeIJ = __ballot(eColJN != 0);
            const bool c0J = c0JN != 0;
            bool chJK[4], chKJ[4];
#pragma unroll
            for (int c = 0; c < 4; ++c) {
                chJK[c] = (&chJKvN.x)[c] != 0;
                chKJ[c] = (y8 == 1) ? (chKJN[c] != 0) : false;
            }

            float accE[16];
            float rs[4] = {0.f, 0.f, 0.f, 0.f};
#pragma unroll
            for (int s = 0; s < 16; ++s) {
                const int I = I0 + s;
                const bool eIJ = (MeIJ >> (hsh + s)) & 1;
                const bool c0I = (Mc0I >> (hsh + s)) & 1;
                const float qT_JI = (&qtvN[s >> 2].x)[s & 3];
                float p_ = 0.f;
#pragma unroll
                for (int c = 0; c < 4; ++c) {
                    const int Kc = K + c;
                    const bool eIK = (ebits >> (4 * s + c)) & 1;
                    const float vv = (&v[s].x)[c];
                    const int mx = J > Kc ? J : Kc;
                    bool nc, o;
                    if (y8 == 0) {
                        nc = eIJ && eIK && (I != Kc) && (J <= Kc) && (J >= I || Kc <= I);
                        o = !((J <= I) && (Kc >= I)) && chJK[c] && (mx != I) && c0K[c] && c0I;
                    } else {
                        nc = eIK && eIJ && (I != J) && (Kc <= J) && (Kc >= I || J <= I);
                        o = !((Kc <= I) && (J >= I)) && chKJ[c] && (mx != I) && c0J && c0I;
                    }
                    p_ += (nc ? (&q_JN.x)[c] : 0.f) * vv;
                    rs[c] += (o ? qT_JI : 0.f) * vv;
                }
                accE[s] = p_;
            }

            // prefetch next unit under reduce + atomics
            if (k < 1) issue_unit7(8 * (Jt0 + 1) + hw);

#pragma unroll
            for (int o = 16; o > 0; o >>= 1) {
#pragma unroll
                for (int s = 0; s < 16; ++s) accE[s] += __shfl_xor(accE[s], o);
            }
            if (lh == 0) {
#pragma unroll
                for (int s = 0; s < 16; ++s)
                    atomicAdd(&base[(y8 == 0 ? 0 : 1) * BSS + off3(b, I0 + s, J)], accE[s]);
            }
#pragma unroll
            for (int c = 0; c < 4; ++c) {
                if (y8 == 0)
                    atomicAdd(&base[2 * BSS + off3(b, J, K + c)], rs[c]);
                else
                    atomicAdd(&base[2 * BSS + off3(b, K + c, J)], rs[c]);
            }
        }
    }
}

extern "C" void kernel_launch(void* const* d_in, const int* in_sizes, int n_in,
                              void* d_out, int out_size, void* d_ws, size_t ws_size,
                              hipStream_t stream) {
    (void)in_sizes; (void)n_in; (void)out_size; (void)ws_size;
    const float* s_const = (const float*)d_in[0];
    const float* s_arg_begin = (const float*)d_in[1];
    const float* s_arg_end = (const float*)d_in[2];
    const float* be = (const float*)d_in[3];
    const float* eb = (const float*)d_in[4];
    const float* bb = (const float*)d_in[5];
    const float* ee = (const float*)d_in[6];
    const float* cb = (const float*)d_in[7];
    const float* ce = (const float*)d_in[8];
    const float* gb = (const float*)d_in[9];
    const float* ge = (const float*)d_in[10];
    const float* sp = (const float*)d_in[11];
    const int* edge = (const int*)d_in[12];
    const int* chart = (const int*)d_in[13];
    float* base = (float*)d_out;
    float* ws = (float*)d_ws;

    for (int it = 0; it < 3; ++it) {
        if (it == 0)
            k_sigmoid<<<dim3(16, 3, BB), dim3(256), 0, stream>>>(s_arg_begin, s_arg_end,
                                                                 s_const, base, ws, 1);
        else
            k_sigmoid<<<dim3(16, 3, BB), dim3(256), 0, stream>>>(base, base + BSS,
                                                                 base + 2 * BSS, base, ws, 0);
        k_terms<<<dim3(2304), dim3(256), 0, stream>>>(be, bb, cb, eb, ee, ce, sp, gb, ge,
                                                      edge, chart, ws, base);
    }
}

// Round 5
// 858.126 us; speedup vs baseline: 1.1198x; 1.1198x over previous
//
#include <hip/hip_runtime.h>

#define BB 4
#define S 128
#define SS (S*S)
#define BSS (BB*SS)

__device__ __forceinline__ int off3(int b, int i, int j) { return (b * S + i) * S + j; }
__device__ __forceinline__ int off4(int b, int i, int j, int k) { return ((b * S + i) * S + j) * S + k; }

// ---------------------------------------------------------------------------
// sigmoid + LDS-tiled transpose (coalesced stores both ways).
// ws planes: qb[0], qe[1], qs[2], qbT[3], qeT[4], qsT[5], each BSS floats.
// ---------------------------------------------------------------------------
__global__ __launch_bounds__(256) void k_sigmoid(const float* __restrict__ sb,
                                                 const float* __restrict__ se,
                                                 const float* __restrict__ ss,
                                                 float* base,
                                                 float* __restrict__ ws, int init) {
    const int b = blockIdx.z, p = blockIdx.y;
    const int ti = blockIdx.x >> 2, tj = blockIdx.x & 3;
    const int col = threadIdx.x & 31, r0 = threadIdx.x >> 5;
    const float* src = (p == 0) ? sb : (p == 1) ? se : ss;

    __shared__ float tile[32][33];
#pragma unroll
    for (int rr = 0; rr < 4; ++rr) {
        const int row = r0 + 8 * rr;
        const int gi = 32 * ti + row, gj = 32 * tj + col;
        const float x = src[off3(b, gi, gj)];
        const float q = 1.0f / (1.0f + __expf(-x));
        ws[p * BSS + off3(b, gi, gj)] = q;
        if (init) base[p * BSS + off3(b, gi, gj)] = x;
        tile[row][col] = q;
    }
    __syncthreads();
#pragma unroll
    for (int rr = 0; rr < 4; ++rr) {
        const int rowo = r0 + 8 * rr;
        ws[(3 + p) * BSS + off3(b, 32 * tj + rowo, 32 * ti + col)] = tile[col][rowo];
    }
}

// ---------------------------------------------------------------------------
// Round-1 body (VGPR=64, no spills) with __launch_bounds__(256,8):
// VGPR<=64 keeps 8 waves/SIMD eligibility -> up to 8 blocks/CU resident.
// Latency-bound kernel (VALU 21%, HBM 25%, LDS 0) -> occupancy is the
// concurrency lever; pipelining attempts cost VGPRs and spilled (R4).
// ---------------------------------------------------------------------------
__global__ __launch_bounds__(256, 8) void k_terms(
    const float* __restrict__ be, const float* __restrict__ bb,
    const float* __restrict__ cb, const float* __restrict__ eb,
    const float* __restrict__ ee, const float* __restrict__ ce,
    const float* __restrict__ sp, const float* __restrict__ gb,
    const float* __restrict__ ge, const int* __restrict__ edge,
    const int* __restrict__ chart, const float* __restrict__ ws,
    float* __restrict__ base) {
    const int b = blockIdx.z, y = blockIdx.y, x = blockIdx.x;
    const int t = threadIdx.x, hw = t >> 5, lh = t & 31, l = t & 63;
    const int K = 4 * lh;

    const float* qb = ws;
    const float* qe = ws + BSS;
    const float* qs = ws + 2 * BSS;
    const float* qbT = ws + 3 * BSS;
    const float* qeT = ws + 4 * BSS;
    const float* qsT = ws + 5 * BSS;

    if (y < 7) {
        const int I = x;
        const float* A;
        int plane;
        switch (y) {
            case 0: A = be; plane = 0; break;
            case 1: A = bb; plane = 0; break;
            case 2: A = cb; plane = 0; break;
            case 3: A = eb; plane = 1; break;
            case 4: A = ee; plane = 1; break;
            case 5: A = ce; plane = 1; break;
            default: A = sp; plane = 2; break;
        }
        const int Iprev = (I + S - 1) & (S - 1);

        // ballot-packed per-j bits (wave-uniform)
        const bool pe0 = edge[off3(b, I, l)] != 0;
        const bool pe1 = edge[off3(b, I, 64 + l)] != 0;
        unsigned long long Mlo = __ballot(pe0), Mhi = __ballot(pe1);
        if (y == 6) {
            const bool pc0 = chart[off3(b, 0, l)] != 0;
            const bool pc1 = chart[off3(b, 0, 64 + l)] != 0;
            const bool ph0 = chart[off3(b, Iprev, l)] != 0;
            const bool ph1 = chart[off3(b, Iprev, 64 + l)] != 0;
            Mlo = __ballot(pc0) & __ballot(ph0);
            Mhi = __ballot(pc1) & __ballot(ph1);
        } else if (y == 3) {  // fold (I != j) into the bit row
            if (I < 64) Mlo &= ~(1ull << I);
            else Mhi &= ~(1ull << (I - 64));
        }

        // per-lane pre-masked coefficients
        const float* qrow = (y == 0 || y == 4) ? qe : (y == 1 || y == 3) ? qb : qs;
        const float4 qv = *(const float4*)&qrow[off3(b, I, K)];
        const int4 ekv = *(const int4*)&edge[off3(b, I, K)];
        const int4 c0kv = *(const int4*)&chart[off3(b, 0, K)];
        float pm[4];
        bool pmask[4];
#pragma unroll
        for (int c = 0; c < 4; ++c) {
            const bool ek = (&ekv.x)[c] != 0;
            const bool c0k = (&c0kv.x)[c] != 0;
            const bool nI = (I != K + c);
            if (y == 0 || y == 1 || y == 4) pm[c] = (ek && nI) ? (&qv.x)[c] : 0.f;
            else if (y == 3) pm[c] = ek ? (&qv.x)[c] : 0.f;
            else if (y == 6) pm[c] = c0k ? (&qv.x)[c] : 0.f;
            pmask[c] = ek && nI;  // for y 2/5
        }
        const int corrSel = (y == 1 || y == 4) ? 1 : (y == 6) ? 2 : 0;
        const float* qT3 = (y == 2) ? qbT : qeT;

        float acc[16];
        if (y == 2 || y == 5) {
#pragma unroll
            for (int jj = 0; jj < 16; ++jj) {
                const int j = 8 * jj + hw;
                const float4 v = *(const float4*)&A[off4(b, I, j, K)];
                const float4 cf = *(const float4*)&qT3[off3(b, j, K)];
                float dot = 0.f;
                float s[4];
#pragma unroll
                for (int c = 0; c < 4; ++c) {
                    s[c] = pmask[c] ? (&cf.x)[c] : 0.f;
                    dot += s[c] * (&v.x)[c];
                }
#pragma unroll
                for (int c = 0; c < 4; ++c)
                    dot -= (K + c == j) ? s[c] * (&v.x)[c] : 0.f;
                const unsigned long long M = (jj < 8) ? Mlo : Mhi;
                const bool bit = (M >> (((jj & 7) << 3) + hw)) & 1;
                acc[jj] = bit ? dot : 0.f;
            }
        } else {
#pragma unroll
            for (int jj = 0; jj < 16; ++jj) {
                const int j = 8 * jj + hw;
                const float4 v = *(const float4*)&A[off4(b, I, j, K)];
                float dot = pm[0] * v.x + pm[1] * v.y + pm[2] * v.z + pm[3] * v.w;
                const int ci = (corrSel == 0) ? 256 : (corrSel == 1) ? j : (I > j ? I : j);
#pragma unroll
                for (int c = 0; c < 4; ++c)
                    dot -= (K + c == ci) ? pm[c] * (&v.x)[c] : 0.f;
                const unsigned long long M = (jj < 8) ? Mlo : Mhi;
                const bool bit = (M >> (((jj & 7) << 3) + hw)) & 1;
                acc[jj] = bit ? dot : 0.f;
            }
        }

#pragma unroll
        for (int o = 16; o > 0; o >>= 1) {
#pragma unroll
            for (int jj = 0; jj < 16; ++jj) acc[jj] += __shfl_xor(acc[jj], o);
        }
        if (lh == 0) {
#pragma unroll
            for (int jj = 0; jj < 16; ++jj)
                atomicAdd(&base[plane * BSS + off3(b, I, 8 * jj + hw)], acc[jj]);
        }
    } else {
        const float* A = (y == 7) ? gb : ge;
        const float* qT = (y == 7) ? qbT : qeT;
        const int Jt = x & 15, Is = x >> 4;
        const int J = 8 * Jt + hw, I0 = 16 * Is;

        const float4 q_J = (y == 7) ? *(const float4*)&qs[off3(b, J, K)]
                                    : *(const float4*)&qsT[off3(b, J, K)];
        const int4 c0Kv = *(const int4*)&chart[off3(b, 0, K)];
        const bool c0J = chart[off3(b, 0, J)] != 0;
        const int Jprev = (J + S - 1) & (S - 1);
        const int4 chJKv = *(const int4*)&chart[off3(b, Jprev, K)];
        bool c0K[4], chJK[4], chKJ[4];
        int mxJ[4];
#pragma unroll
        for (int c = 0; c < 4; ++c) {
            c0K[c] = (&c0Kv.x)[c] != 0;
            chJK[c] = (&chJKv.x)[c] != 0;
            chKJ[c] = (y == 8) ? (chart[off3(b, (K + c + S - 1) & (S - 1), J)] != 0) : false;
            mxJ[c] = J > (K + c) ? J : (K + c);
        }

        // ballots: eIJ bits and c0I bits for I = I0..I0+15 (this lane's J)
        const unsigned long long MeIJ = __ballot(edge[off3(b, I0 + (l & 15), J)] != 0);
        const unsigned long long Mc0I = __ballot(chart[off3(b, 0, I0 + (l & 15))] != 0);
        const int hsh = l & 32;

        float accE[16];
        float rs[4] = {0.f, 0.f, 0.f, 0.f};

#pragma unroll
        for (int s = 0; s < 16; ++s) {
            const int I = I0 + s;
            const float4 v = *(const float4*)&A[off4(b, I, J, K)];
            const int4 eIKv = *(const int4*)&edge[off3(b, I, K)];
            const bool eIJ = (MeIJ >> (hsh + s)) & 1;
            const bool c0I = (Mc0I >> (hsh + s)) & 1;
            const float qT_JI = qT[off3(b, J, I)];

            float p = 0.f;
#pragma unroll
            for (int c = 0; c < 4; ++c) {
                const int Kc = K + c;
                const bool eIK = (&eIKv.x)[c] != 0;
                const float vv = (&v.x)[c];
                bool nc, o;
                if (y == 7) {
                    nc = eIJ && eIK && (I != Kc) && (J <= Kc) && (J >= I || Kc <= I);
                    o = !((J <= I) && (Kc >= I)) && chJK[c] && (mxJ[c] != I) && c0K[c] && c0I;
                } else {
                    nc = eIK && eIJ && (I != J) && (Kc <= J) && (Kc >= I || J <= I);
                    o = !((Kc <= I) && (J >= I)) && chKJ[c] && (mxJ[c] != I) && c0J && c0I;
                }
                p += (nc ? (&q_J.x)[c] : 0.f) * vv;
                rs[c] += (o ? qT_JI : 0.f) * vv;
            }
            accE[s] = p;
        }

#pragma unroll
        for (int o = 16; o > 0; o >>= 1) {
#pragma unroll
            for (int s = 0; s < 16; ++s) accE[s] += __shfl_xor(accE[s], o);
        }
        if (lh == 0) {
#pragma unroll
            for (int s = 0; s < 16; ++s)
                atomicAdd(&base[(y == 7 ? 0 : 1) * BSS + off3(b, I0 + s, J)], accE[s]);
        }

#pragma unroll
        for (int c = 0; c < 4; ++c) {
            if (y == 7)
                atomicAdd(&base[2 * BSS + off3(b, J, K + c)], rs[c]);
            else
                atomicAdd(&base[2 * BSS + off3(b, K + c, J)], rs[c]);
        }
    }
}

extern "C" void kernel_launch(void* const* d_in, const int* in_sizes, int n_in,
                              void* d_out, int out_size, void* d_ws, size_t ws_size,
                              hipStream_t stream) {
    (void)in_sizes; (void)n_in; (void)out_size; (void)ws_size;
    const float* s_const = (const float*)d_in[0];
    const float* s_arg_begin = (const float*)d_in[1];
    const float* s_arg_end = (const float*)d_in[2];
    const float* be = (const float*)d_in[3];
    const float* eb = (const float*)d_in[4];
    const float* bb = (const float*)d_in[5];
    const float* ee = (const float*)d_in[6];
    const float* cb = (const float*)d_in[7];
    const float* ce = (const float*)d_in[8];
    const float* gb = (const float*)d_in[9];
    const float* ge = (const float*)d_in[10];
    const float* sp = (const float*)d_in[11];
    const int* edge = (const int*)d_in[12];
    const int* chart = (const int*)d_in[13];
    float* base = (float*)d_out;
    float* ws = (float*)d_ws;

    for (int it = 0; it < 3; ++it) {
        if (it == 0)
            k_sigmoid<<<dim3(16, 3, BB), dim3(256), 0, stream>>>(s_arg_begin, s_arg_end,
                                                                 s_const, base, ws, 1);
        else
            k_sigmoid<<<dim3(16, 3, BB), dim3(256), 0, stream>>>(base, base + BSS,
                                                                 base + 2 * BSS, base, ws, 0);
        k_terms<<<dim3(S, 9, BB), dim3(256), 0, stream>>>(be, bb, cb, eb, ee, ce, sp, gb, ge,
                                                          edge, chart, ws, base);
    }
}

// Round 6
// 565.507 us; speedup vs baseline: 1.6993x; 1.5174x over previous
//
#include <hip/hip_runtime.h>

#define BB 4
#define S 128
#define SS (S*S)
#define BSS (BB*SS)

// ws planes (each BSS floats = 256 KB), 23 total = 5.75 MB:
// 0..5  : qb qe qs qbT qeT qsT
// 6..12 : per-y edge partials (y=0..6)
// 13,14 : accE partials (gb, ge)
// 15..22: rs partials, 4 per y8 (Is2=0..3)
#define WPY0 6
#define WAE0 13
#define WAE1 14
#define WRS0 15

__device__ __forceinline__ int off3(int b, int i, int j) { return (b * S + i) * S + j; }
__device__ __forceinline__ int off4(int b, int i, int j, int k) { return ((b * S + i) * S + j) * S + k; }

// ---------------------------------------------------------------------------
// combine + sigmoid + LDS-tiled transpose.
// mode 0: base = src, q = sigmoid(base)
// mode 1: base += partials, q = sigmoid(base)
// mode 2: base += partials only (final)
// ---------------------------------------------------------------------------
__global__ __launch_bounds__(256) void k_sigmoid(const float* __restrict__ sb,
                                                 const float* __restrict__ se,
                                                 const float* __restrict__ ss,
                                                 float* __restrict__ base,
                                                 float* __restrict__ ws, int mode) {
    const int b = blockIdx.z, p = blockIdx.y;
    const int ti = blockIdx.x >> 2, tj = blockIdx.x & 3;
    const int col = threadIdx.x & 31, r0 = threadIdx.x >> 5;
    __shared__ float tile[32][33];
    float* bp = base + p * BSS;

#pragma unroll
    for (int rr = 0; rr < 4; ++rr) {
        const int row = r0 + 8 * rr;
        const int gi = 32 * ti + row, gj = 32 * tj + col;
        const int idx = off3(b, gi, gj);
        float v;
        if (mode == 0) {
            const float* src = (p == 0) ? sb : (p == 1) ? se : ss;
            v = src[idx];
        } else {
            v = bp[idx];
            if (p == 0) {
                v += ws[(WPY0 + 0) * BSS + idx] + ws[(WPY0 + 1) * BSS + idx] +
                     ws[(WPY0 + 2) * BSS + idx] + ws[WAE0 * BSS + idx];
            } else if (p == 1) {
                v += ws[(WPY0 + 3) * BSS + idx] + ws[(WPY0 + 4) * BSS + idx] +
                     ws[(WPY0 + 5) * BSS + idx] + ws[WAE1 * BSS + idx];
            } else {
                v += ws[(WPY0 + 6) * BSS + idx];
#pragma unroll
                for (int n = 0; n < 8; ++n) v += ws[(WRS0 + n) * BSS + idx];
            }
        }
        bp[idx] = v;
        if (mode < 2) {
            const float q = 1.0f / (1.0f + __expf(-v));
            ws[p * BSS + idx] = q;
            tile[row][col] = q;
        }
    }
    if (mode == 2) return;
    __syncthreads();
#pragma unroll
    for (int rr = 0; rr < 4; ++rr) {
        const int rowo = r0 + 8 * rr;
        ws[(3 + p) * BSS + off3(b, 32 * tj + rowo, 32 * ti + col)] = tile[col][rowo];
    }
}

// ---------------------------------------------------------------------------
// Edge terms (old y<7), R3 body, ZERO atomics: row store to per-y partial
// plane via LDS repack. grid = (128, 7, B).
// ---------------------------------------------------------------------------
__global__ __launch_bounds__(256, 3) void k_edge(
    const float* __restrict__ be, const float* __restrict__ bb,
    const float* __restrict__ cb, const float* __restrict__ eb,
    const float* __restrict__ ee, const float* __restrict__ ce,
    const float* __restrict__ sp, const int* __restrict__ edge,
    const int* __restrict__ chart, float* __restrict__ ws) {
    const int b = blockIdx.z, y = blockIdx.y, x = blockIdx.x;
    const int t = threadIdx.x, hw = t >> 5, lh = t & 31, l = t & 63;
    const int K = 4 * lh;
    __shared__ float rowbuf[128];

    const float* qb = ws;
    const float* qe = ws + BSS;
    const float* qs = ws + 2 * BSS;
    const float* qbT = ws + 3 * BSS;
    const float* qeT = ws + 4 * BSS;

    const int I = x;
    const float* A;
    switch (y) {
        case 0: A = be; break;
        case 1: A = bb; break;
        case 2: A = cb; break;
        case 3: A = eb; break;
        case 4: A = ee; break;
        case 5: A = ce; break;
        default: A = sp; break;
    }
    const int Iprev = (I + S - 1) & (S - 1);

    // ballot-packed per-j bits (wave-uniform)
    const bool pe0 = edge[off3(b, I, l)] != 0;
    const bool pe1 = edge[off3(b, I, 64 + l)] != 0;
    unsigned long long Mlo = __ballot(pe0), Mhi = __ballot(pe1);
    if (y == 6) {
        const bool pc0 = chart[off3(b, 0, l)] != 0;
        const bool pc1 = chart[off3(b, 0, 64 + l)] != 0;
        const bool ph0 = chart[off3(b, Iprev, l)] != 0;
        const bool ph1 = chart[off3(b, Iprev, 64 + l)] != 0;
        Mlo = __ballot(pc0) & __ballot(ph0);
        Mhi = __ballot(pc1) & __ballot(ph1);
    } else if (y == 3) {
        if (I < 64) Mlo &= ~(1ull << I);
        else Mhi &= ~(1ull << (I - 64));
    }

    // per-lane pre-masked coefficients
    const float* qrow = (y == 0 || y == 4) ? qe : (y == 1 || y == 3) ? qb : qs;
    const float4 qv = *(const float4*)&qrow[off3(b, I, K)];
    const int4 ekv = *(const int4*)&edge[off3(b, I, K)];
    const int4 c0kv = *(const int4*)&chart[off3(b, 0, K)];
    float pm[4];
    bool pmask[4];
#pragma unroll
    for (int c = 0; c < 4; ++c) {
        const bool ek = (&ekv.x)[c] != 0;
        const bool c0k = (&c0kv.x)[c] != 0;
        const bool nI = (I != K + c);
        if (y == 0 || y == 1 || y == 4) pm[c] = (ek && nI) ? (&qv.x)[c] : 0.f;
        else if (y == 3) pm[c] = ek ? (&qv.x)[c] : 0.f;
        else if (y == 6) pm[c] = c0k ? (&qv.x)[c] : 0.f;
        pmask[c] = ek && nI;  // for y 2/5
    }
    const int corrSel = (y == 1 || y == 4) ? 1 : (y == 6) ? 2 : 0;
    const float* qT3 = (y == 2) ? qbT : qeT;

    float acc[16];
    if (y == 2 || y == 5) {
        // two 8-deep batches of (A, coeff) loads
#pragma unroll
        for (int h = 0; h < 2; ++h) {
            float4 va[8], cf[8];
#pragma unroll
            for (int u = 0; u < 8; ++u) {
                const int j = 8 * (8 * h + u) + hw;
                va[u] = *(const float4*)&A[off4(b, I, j, K)];
                cf[u] = *(const float4*)&qT3[off3(b, j, K)];
            }
#pragma unroll
            for (int u = 0; u < 8; ++u) {
                const int jj = 8 * h + u;
                const int j = 8 * jj + hw;
                float dot = 0.f;
                float s_[4];
#pragma unroll
                for (int c = 0; c < 4; ++c) {
                    s_[c] = pmask[c] ? (&cf[u].x)[c] : 0.f;
                    dot += s_[c] * (&va[u].x)[c];
                }
#pragma unroll
                for (int c = 0; c < 4; ++c)
                    dot -= (K + c == j) ? s_[c] * (&va[u].x)[c] : 0.f;
                const unsigned long long M = (jj < 8) ? Mlo : Mhi;
                const bool bit = (M >> (((jj & 7) << 3) + hw)) & 1;
                acc[jj] = bit ? dot : 0.f;
            }
        }
    } else {
        // all 16 A-row float4s prefetched to registers before compute
        float4 v[16];
#pragma unroll
        for (int jj = 0; jj < 16; ++jj)
            v[jj] = *(const float4*)&A[off4(b, I, 8 * jj + hw, K)];
#pragma unroll
        for (int jj = 0; jj < 16; ++jj) {
            const int j = 8 * jj + hw;
            float dot = pm[0] * v[jj].x + pm[1] * v[jj].y + pm[2] * v[jj].z + pm[3] * v[jj].w;
            const int ci = (corrSel == 0) ? 256 : (corrSel == 1) ? j : (I > j ? I : j);
#pragma unroll
            for (int c = 0; c < 4; ++c)
                dot -= (K + c == ci) ? pm[c] * (&v[jj].x)[c] : 0.f;
            const unsigned long long M = (jj < 8) ? Mlo : Mhi;
            const bool bit = (M >> (((jj & 7) << 3) + hw)) & 1;
            acc[jj] = bit ? dot : 0.f;
        }
    }

#pragma unroll
    for (int o = 16; o > 0; o >>= 1) {
#pragma unroll
        for (int jj = 0; jj < 16; ++jj) acc[jj] += __shfl_xor(acc[jj], o);
    }
    // pack row I into LDS, then one coalesced float4 row store (NO atomics)
    if (lh == 0) {
#pragma unroll
        for (int jj = 0; jj < 16; ++jj) rowbuf[8 * jj + hw] = acc[jj];
    }
    __syncthreads();
    if (t < 32)
        *(float4*)&ws[(WPY0 + y) * BSS + off3(b, I, 4 * t)] = *(const float4*)&rowbuf[4 * t];
}

// ---------------------------------------------------------------------------
// Span terms (old y7/8), ZERO atomics. grid = (64, 2, B).
// x: Jt = x&15, Is2 = x>>4 (0..3). Block covers J=8Jt..+7(hw), I in
// [32*Is2, 32*Is2+32) processed in two 16-halves (R3 body per half).
// rs accumulates across all 32 I in registers -> single-writer plane store.
// ---------------------------------------------------------------------------
__global__ __launch_bounds__(256, 3) void k_span(
    const float* __restrict__ gb, const float* __restrict__ ge,
    const int* __restrict__ edge, const int* __restrict__ chart,
    float* __restrict__ ws) {
    const int b = blockIdx.z, y8 = blockIdx.y, x = blockIdx.x;
    const int t = threadIdx.x, hw = t >> 5, lh = t & 31, l = t & 63;
    const int K = 4 * lh;

    const float* qs = ws + 2 * BSS;
    const float* qbT = ws + 3 * BSS;
    const float* qeT = ws + 4 * BSS;
    const float* qsT = ws + 5 * BSS;

    const float* A = (y8 == 0) ? gb : ge;
    const float* qT = (y8 == 0) ? qbT : qeT;
    const int Jt = x & 15, Is2 = x >> 4;
    const int J = 8 * Jt + hw;
    const int hsh = l & 32;

    // ---- J/K-dependent block constants (hoisted across halves) ----
    const float4 q_J = (y8 == 0) ? *(const float4*)&qs[off3(b, J, K)]
                                 : *(const float4*)&qsT[off3(b, J, K)];
    const int4 c0Kv = *(const int4*)&chart[off3(b, 0, K)];
    const bool c0J = chart[off3(b, 0, J)] != 0;
    const int Jprev = (J + S - 1) & (S - 1);
    const int4 chJKv = *(const int4*)&chart[off3(b, Jprev, K)];
    bool c0K[4], chJK[4], chKJ[4];
    int mxJ[4];
#pragma unroll
    for (int c = 0; c < 4; ++c) {
        c0K[c] = (&c0Kv.x)[c] != 0;
        chJK[c] = (&chJKv.x)[c] != 0;
        chKJ[c] = (y8 == 1) ? (chart[off3(b, (K + c + S - 1) & (S - 1), J)] != 0) : false;
        mxJ[c] = J > (K + c) ? J : (K + c);
    }

    float rs[4] = {0.f, 0.f, 0.f, 0.f};

#pragma unroll
    for (int h = 0; h < 2; ++h) {
        const int I0 = 32 * Is2 + 16 * h;

        const unsigned long long MeIJ = __ballot(edge[off3(b, I0 + (l & 15), J)] != 0);
        const unsigned long long Mc0I = __ballot(chart[off3(b, 0, I0 + (l & 15))] != 0);

        // qT row J, cols I0..I0+15
        float4 qtv[4];
#pragma unroll
        for (int q4 = 0; q4 < 4; ++q4)
            qtv[q4] = *(const float4*)&qT[off3(b, J, I0 + 4 * q4)];

        float accE[16];
        // two 8-deep batches of (A float4, edge int4) loads
#pragma unroll
        for (int hf = 0; hf < 2; ++hf) {
            float4 v[8];
            int4 ev[8];
#pragma unroll
            for (int u = 0; u < 8; ++u) {
                const int I = I0 + 8 * hf + u;
                v[u] = *(const float4*)&A[off4(b, I, J, K)];
                ev[u] = *(const int4*)&edge[off3(b, I, K)];
            }
#pragma unroll
            for (int u = 0; u < 8; ++u) {
                const int s = 8 * hf + u;
                const int I = I0 + s;
                const bool eIJ = (MeIJ >> (hsh + s)) & 1;
                const bool c0I = (Mc0I >> (hsh + s)) & 1;
                const float qT_JI = (&qtv[s >> 2].x)[s & 3];

                float p_ = 0.f;
#pragma unroll
                for (int c = 0; c < 4; ++c) {
                    const int Kc = K + c;
                    const bool eIK = (&ev[u].x)[c] != 0;
                    const float vv = (&v[u].x)[c];
                    bool nc, o;
                    if (y8 == 0) {
                        nc = eIJ && eIK && (I != Kc) && (J <= Kc) && (J >= I || Kc <= I);
                        o = !((J <= I) && (Kc >= I)) && chJK[c] && (mxJ[c] != I) && c0K[c] && c0I;
                    } else {
                        nc = eIK && eIJ && (I != J) && (Kc <= J) && (Kc >= I || J <= I);
                        o = !((Kc <= I) && (J >= I)) && chKJ[c] && (mxJ[c] != I) && c0J && c0I;
                    }
                    p_ += (nc ? (&q_J.x)[c] : 0.f) * vv;
                    rs[c] += (o ? qT_JI : 0.f) * vv;
                }
                accE[s] = p_;
            }
        }

#pragma unroll
        for (int o = 16; o > 0; o >>= 1) {
#pragma unroll
            for (int s = 0; s < 16; ++s) accE[s] += __shfl_xor(accE[s], o);
        }
        if (lh == 0) {
#pragma unroll
            for (int s = 0; s < 16; ++s)
                ws[((y8 == 0) ? WAE0 : WAE1) * BSS + off3(b, I0 + s, J)] = accE[s];
        }
    }

    // rs: single-writer per (y8, Is2) plane — plain stores
    if (y8 == 0) {
        *(float4*)&ws[(WRS0 + Is2) * BSS + off3(b, J, K)] =
            make_float4(rs[0], rs[1], rs[2], rs[3]);
    } else {
#pragma unroll
        for (int c = 0; c < 4; ++c)
            ws[(WRS0 + 4 + Is2) * BSS + off3(b, K + c, J)] = rs[c];
    }
}

extern "C" void kernel_launch(void* const* d_in, const int* in_sizes, int n_in,
                              void* d_out, int out_size, void* d_ws, size_t ws_size,
                              hipStream_t stream) {
    (void)in_sizes; (void)n_in; (void)out_size; (void)ws_size;
    const float* s_const = (const float*)d_in[0];
    const float* s_arg_begin = (const float*)d_in[1];
    const float* s_arg_end = (const float*)d_in[2];
    const float* be = (const float*)d_in[3];
    const float* eb = (const float*)d_in[4];
    const float* bb = (const float*)d_in[5];
    const float* ee = (const float*)d_in[6];
    const float* cb = (const float*)d_in[7];
    const float* ce = (const float*)d_in[8];
    const float* gb = (const float*)d_in[9];
    const float* ge = (const float*)d_in[10];
    const float* sp = (const float*)d_in[11];
    const int* edge = (const int*)d_in[12];
    const int* chart = (const int*)d_in[13];
    float* base = (float*)d_out;
    float* ws = (float*)d_ws;

    for (int it = 0; it < 3; ++it) {
        k_sigmoid<<<dim3(16, 3, BB), dim3(256), 0, stream>>>(s_arg_begin, s_arg_end, s_const,
                                                             base, ws, it == 0 ? 0 : 1);
        k_edge<<<dim3(S, 7, BB), dim3(256), 0, stream>>>(be, bb, cb, eb, ee, ce, sp,
                                                         edge, chart, ws);
        k_span<<<dim3(64, 2, BB), dim3(256), 0, stream>>>(gb, ge, edge, chart, ws);
    }
    k_sigmoid<<<dim3(16, 3, BB), dim3(256), 0, stream>>>(s_arg_begin, s_arg_end, s_const,
                                                         base, ws, 2);
}